// Round 3
// baseline (1100.335 us; speedup 1.0000x reference)
//
#include <hip/hip_runtime.h>

// ---------------------------------------------------------------------------
// ModifiedTransformerEncoderLayer on MI355X (gfx950)
// B=4096 J=17 D=512 H=8 DK=64, M=B*J=69632.
// I/O dtype: float32 (per reference setup_inputs — jnp.float32 everywhere);
// mask_rows/cols int32. Compute: bf16 MFMA GEMMs with f32 accumulate;
// intermediates bf16; residual/LN params read as f32; output written f32.
//
// Pipeline:
//   convert_src    : src f32 -> bf16 SRCB
//   prep_transpose : W (f32) -> W^T bf16 [N][K] layouts
//   prep_small     : bias concat (f32), adjacency softmax + neighbor lists
//   gemm_bt        : QKV = SRCB @ [Wq|Wk|Wv]^T + bias   [M,1536] bf16
//   attn_kernel    : per-(b,h) softmax(QK^T/8)V -> O    [M,512]  bf16
//   gemm_bt        : ATT = O @ Wo^T + bo                [M,512]  bf16
//   ln_res_kernel  : X = LN1(src_f32 + ATT)             [M,512]  bf16
//   gemm_bt        : H01 = X @ [W0|W1]^T                [M,1024] bf16
//   gcn_ln_kernel  : out = LN2(X + A*h0/h1 + b_gcn)     [M,512]  f32
//
// ws layout (peak 0x11400000 = 276.1 MiB):
//   WT1 @0x000000  WT2 @0x180000  WT3 @0x200000  smalls @0x300000
//   SRCB @0x0400000 (0x4400000)    [phase 1 only]
//   QKV  @0x4800000 (0xCC00000)    [phases 1-2]
//   O    @0x0400000 (0x4400000)    [phases 2-3, overwrites dead SRCB]
//   ATT  @0x4800000 (0x4400000)    [phases 3-4, QKV head dead]
//   X    @0x8C00000 (0x4400000)    [phases 4-6]
//   H01  @0x0400000 (0x8800000)    [phases 5-6, O+ATT dead]
// ---------------------------------------------------------------------------

typedef __attribute__((ext_vector_type(4))) float floatx4;
typedef __attribute__((ext_vector_type(8))) short short8;

__device__ __forceinline__ float bf2f(unsigned short u) {
  union { unsigned int i; float f; } x;
  x.i = ((unsigned int)u) << 16;
  return x.f;
}

__device__ __forceinline__ unsigned short f2bf(float f) {
  union { float f; unsigned int i; } x;
  x.f = f;
  unsigned int r = x.i + 0x7fffu + ((x.i >> 16) & 1u);  // RNE
  return (unsigned short)(r >> 16);
}

__device__ __forceinline__ void unpack8(uint4 u, float* f) {
  unsigned int uu[4] = {u.x, u.y, u.z, u.w};
#pragma unroll
  for (int i = 0; i < 4; ++i) {
    f[2 * i]     = bf2f((unsigned short)(uu[i] & 0xffffu));
    f[2 * i + 1] = bf2f((unsigned short)(uu[i] >> 16));
  }
}

__device__ __forceinline__ uint4 pack8(const float* f) {
  unsigned int uu[4];
#pragma unroll
  for (int i = 0; i < 4; ++i)
    uu[i] = (unsigned int)f2bf(f[2 * i]) | ((unsigned int)f2bf(f[2 * i + 1]) << 16);
  uint4 u; u.x = uu[0]; u.y = uu[1]; u.z = uu[2]; u.w = uu[3];
  return u;
}

__device__ __forceinline__ float wave_sum(float v) {
#pragma unroll
  for (int m = 1; m < 64; m <<= 1) v += __shfl_xor(v, m, 64);
  return v;
}

// ---------------------------------------------------------------------------
// src f32 -> bf16, 8 elems/thread. n must be divisible by 8.
// ---------------------------------------------------------------------------
__global__ __launch_bounds__(256) void convert_src(
    const float* __restrict__ in, unsigned short* __restrict__ out) {
  const size_t i = ((size_t)blockIdx.x * 256 + threadIdx.x) * 8;
  const float4 a = *(const float4*)(in + i);
  const float4 b = *(const float4*)(in + i + 4);
  const float f[8] = {a.x, a.y, a.z, a.w, b.x, b.y, b.z, b.w};
  *(uint4*)(out + i) = pack8(f);
}

// ---------------------------------------------------------------------------
// GEMM: C[M,N] = A[M,512] @ BT[N,512]^T (+ bias[N]), bf16 in/out, f32 accum.
// 128x128 tile, BK=32, 4 waves of 4x4 16x16x32 MFMA. Synchronous staging.
// ---------------------------------------------------------------------------
__global__ __launch_bounds__(256) void gemm_bt(
    const unsigned short* __restrict__ A,
    const unsigned short* __restrict__ BT,
    const float* __restrict__ bias,
    unsigned short* __restrict__ C, int N) {
  __shared__ unsigned short As[128 * 32];
  __shared__ unsigned short Bs[128 * 32];
  const int t = threadIdx.x;
  const int wave = t >> 6;
  const int lane = t & 63;
  const int wm = wave >> 1, wn = wave & 1;
  const long rowBase = (long)blockIdx.x * 128;
  const long colBase = (long)blockIdx.y * 128;

  const unsigned short* a0 = A + (size_t)rowBase * 512;
  const unsigned short* b0 = BT + (size_t)colBase * 512;

  floatx4 acc[4][4];
#pragma unroll
  for (int i = 0; i < 4; ++i)
#pragma unroll
    for (int j = 0; j < 4; ++j) acc[i][j] = (floatx4){0.f, 0.f, 0.f, 0.f};

  // chunk c <-> (row=c>>2, kchunk=c&3); thread t owns chunks t and t+256.
  // LDS offset of chunk c = c*8 shorts (row*32 + kchunk*8 == c*8).
  const size_t gOffA0 = ((size_t)(t >> 2)) * 512 + (size_t)(t & 3) * 8;
  const size_t gOffA1 = ((size_t)((t + 256) >> 2)) * 512 + (size_t)(t & 3) * 8;

  const int am = lane & 15;
  const int aq = (lane >> 4) << 3;

  for (int k0 = 0; k0 < 512; k0 += 32) {
    const uint4 va0 = *(const uint4*)(a0 + gOffA0 + k0);
    const uint4 va1 = *(const uint4*)(a0 + gOffA1 + k0);
    const uint4 vb0 = *(const uint4*)(b0 + gOffA0 + k0);
    const uint4 vb1 = *(const uint4*)(b0 + gOffA1 + k0);
    __syncthreads();  // previous tile fully consumed
    *(uint4*)&As[(size_t)t * 8]         = va0;
    *(uint4*)&As[(size_t)(t + 256) * 8] = va1;
    *(uint4*)&Bs[(size_t)t * 8]         = vb0;
    *(uint4*)&Bs[(size_t)(t + 256) * 8] = vb1;
    __syncthreads();  // tile visible

    short8 af[4], bf[4];
#pragma unroll
    for (int i = 0; i < 4; ++i)
      af[i] = *(const short8*)&As[(wm * 64 + i * 16 + am) * 32 + aq];
#pragma unroll
    for (int j = 0; j < 4; ++j)
      bf[j] = *(const short8*)&Bs[(wn * 64 + j * 16 + am) * 32 + aq];
#pragma unroll
    for (int i = 0; i < 4; ++i)
#pragma unroll
      for (int j = 0; j < 4; ++j)
        acc[i][j] = __builtin_amdgcn_mfma_f32_16x16x32_bf16(af[i], bf[j], acc[i][j], 0, 0, 0);
  }

  // epilogue: C/D layout col=lane&15, row=(lane>>4)*4+reg  [m89-verified]
  const int q4 = (lane >> 4) << 2;
#pragma unroll
  for (int i = 0; i < 4; ++i) {
#pragma unroll
    for (int j = 0; j < 4; ++j) {
      const long col = colBase + wn * 64 + j * 16 + am;
      const float badd = bias ? bias[col] : 0.f;
      const long rowa = rowBase + wm * 64 + i * 16 + q4;
#pragma unroll
      for (int r = 0; r < 4; ++r)
        C[(size_t)(rowa + r) * N + col] = f2bf(acc[i][j][r] + badd);
    }
  }
}

// ---------------------------------------------------------------------------
// Per-(b,h) attention: q,k,v from QKV[M,1536] bf16; o[M,512] bf16, col=h*64+e
// ---------------------------------------------------------------------------
__global__ __launch_bounds__(256) void attn_kernel(
    const unsigned short* __restrict__ qkv, unsigned short* __restrict__ o) {
  const int b = blockIdx.x, h = blockIdx.y;
  __shared__ float q[17][64], k[17][64], v[17][64];
  __shared__ float S[17][17];
  const int t = threadIdx.x;
  const unsigned short* base = qkv + (size_t)b * 17 * 1536 + h * 64;

  for (int idx = t; idx < 3 * 136; idx += 256) {  // 136 = 17 rows * 8 chunks
    const int m = idx / 136, rem = idx - m * 136;
    const int r = rem >> 3, e0 = (rem & 7) << 3;
    uint4 u = *(const uint4*)(base + (size_t)r * 1536 + m * 512 + e0);
    float f[8];
    unpack8(u, f);
    float(*dst)[64] = (m == 0) ? q : (m == 1) ? k : v;
#pragma unroll
    for (int e = 0; e < 8; ++e) dst[r][e0 + e] = f[e];
  }
  __syncthreads();

  for (int idx = t; idx < 289; idx += 256) {
    const int j = idx / 17, kk = idx - j * 17;
    float s = 0.f;
#pragma unroll 8
    for (int e = 0; e < 64; ++e) s += q[j][e] * k[kk][e];
    S[j][kk] = s * 0.125f;  // / sqrt(64)
  }
  __syncthreads();

  if (t < 17) {
    float m = -1e30f;
#pragma unroll
    for (int kk = 0; kk < 17; ++kk) m = fmaxf(m, S[t][kk]);
    float tmp[17], sum = 0.f;
#pragma unroll
    for (int kk = 0; kk < 17; ++kk) { tmp[kk] = __expf(S[t][kk] - m); sum += tmp[kk]; }
    const float inv = 1.f / sum;
#pragma unroll
    for (int kk = 0; kk < 17; ++kk) S[t][kk] = tmp[kk] * inv;
  }
  __syncthreads();

  unsigned short* ob = o + (size_t)b * 17 * 512 + h * 64;
  for (int idx = t; idx < 136; idx += 256) {
    const int j = idx >> 3, e0 = (idx & 7) << 3;
    float ov[8] = {0, 0, 0, 0, 0, 0, 0, 0};
#pragma unroll
    for (int kk = 0; kk < 17; ++kk) {
      const float a = S[j][kk];
#pragma unroll
      for (int e = 0; e < 8; ++e) ov[e] += a * v[kk][e0 + e];
    }
    *(uint4*)(ob + (size_t)j * 512 + e0) = pack8(ov);
  }
}

// ---------------------------------------------------------------------------
// X = LN1(src_f32 + att_bf16; g,beta f32) -> bf16. One wave per row.
// ---------------------------------------------------------------------------
__global__ __launch_bounds__(256) void ln_res_kernel(
    const float* __restrict__ a, const unsigned short* __restrict__ b,
    const float* __restrict__ g, const float* __restrict__ beta,
    unsigned short* __restrict__ out) {
  const long row = (long)blockIdx.x * 4 + (threadIdx.x >> 6);
  const int lane = threadIdx.x & 63;
  const int d0 = lane * 8;

  const float4 a0 = *(const float4*)(a + (size_t)row * 512 + d0);
  const float4 a1 = *(const float4*)(a + (size_t)row * 512 + d0 + 4);
  const float fa[8] = {a0.x, a0.y, a0.z, a0.w, a1.x, a1.y, a1.z, a1.w};
  float fb[8], vals[8];
  unpack8(*(const uint4*)(b + (size_t)row * 512 + d0), fb);
  float s = 0.f, s2 = 0.f;
#pragma unroll
  for (int i = 0; i < 8; ++i) {
    vals[i] = fa[i] + fb[i];
    s += vals[i];
    s2 += vals[i] * vals[i];
  }
  const float mean = wave_sum(s) * (1.f / 512.f);
  const float var = wave_sum(s2) * (1.f / 512.f) - mean * mean;
  const float rs = rsqrtf(var + 1e-5f);

  const float4 g0 = *(const float4*)(g + d0);
  const float4 g1 = *(const float4*)(g + d0 + 4);
  const float4 b0 = *(const float4*)(beta + d0);
  const float4 b1 = *(const float4*)(beta + d0 + 4);
  const float fg[8]  = {g0.x, g0.y, g0.z, g0.w, g1.x, g1.y, g1.z, g1.w};
  const float fbt[8] = {b0.x, b0.y, b0.z, b0.w, b1.x, b1.y, b1.z, b1.w};
  float y[8];
#pragma unroll
  for (int i = 0; i < 8; ++i) y[i] = (vals[i] - mean) * rs * fg[i] + fbt[i];
  *(uint4*)(out + (size_t)row * 512 + d0) = pack8(y);
}

// ---------------------------------------------------------------------------
// out_f32 = LN2(x + gcn + b_gcn); gcn = Adiag[j]*h0[row] + sum_nbr w*h1[b,k]
// ---------------------------------------------------------------------------
__global__ __launch_bounds__(256) void gcn_ln_kernel(
    const unsigned short* __restrict__ x, const unsigned short* __restrict__ h01,
    const float* __restrict__ Adiag, const int* __restrict__ cnt,
    const int* __restrict__ nbrk, const float* __restrict__ nbrw,
    const float* __restrict__ bgcn,
    const float* __restrict__ g, const float* __restrict__ beta,
    float* __restrict__ out) {
  const long row = (long)blockIdx.x * 4 + (threadIdx.x >> 6);
  const int lane = threadIdx.x & 63;
  const int b = (int)(row / 17);
  const int j = (int)(row - (long)b * 17);
  const int d0 = lane * 8;

  float accv[8];
  {
    const float w = Adiag[j];
    float f[8];
    unpack8(*(const uint4*)(h01 + (size_t)row * 1024 + d0), f);
#pragma unroll
    for (int i = 0; i < 8; ++i) accv[i] = w * f[i];
  }
  const int c = cnt[j];
  for (int nb = 0; nb < c; ++nb) {
    const int kk = nbrk[j * 8 + nb];
    const float w = nbrw[j * 8 + nb];
    float f[8];
    unpack8(*(const uint4*)(h01 + ((size_t)b * 17 + kk) * 1024 + 512 + d0), f);
#pragma unroll
    for (int i = 0; i < 8; ++i) accv[i] += w * f[i];
  }

  float fx[8], vals[8];
  unpack8(*(const uint4*)(x + (size_t)row * 512 + d0), fx);
  const float4 bg0 = *(const float4*)(bgcn + d0);
  const float4 bg1 = *(const float4*)(bgcn + d0 + 4);
  const float fbg[8] = {bg0.x, bg0.y, bg0.z, bg0.w, bg1.x, bg1.y, bg1.z, bg1.w};
  float s = 0.f, s2 = 0.f;
#pragma unroll
  for (int i = 0; i < 8; ++i) {
    vals[i] = fx[i] + accv[i] + fbg[i];
    s += vals[i];
    s2 += vals[i] * vals[i];
  }
  const float mean = wave_sum(s) * (1.f / 512.f);
  const float var = wave_sum(s2) * (1.f / 512.f) - mean * mean;
  const float rs = rsqrtf(var + 1e-5f);

  const float4 g0 = *(const float4*)(g + d0);
  const float4 g1 = *(const float4*)(g + d0 + 4);
  const float4 bb0 = *(const float4*)(beta + d0);
  const float4 bb1 = *(const float4*)(beta + d0 + 4);
  const float fg[8]  = {g0.x, g0.y, g0.z, g0.w, g1.x, g1.y, g1.z, g1.w};
  const float fbt[8] = {bb0.x, bb0.y, bb0.z, bb0.w, bb1.x, bb1.y, bb1.z, bb1.w};
  float4 y0, y1;
  y0.x = (vals[0] - mean) * rs * fg[0] + fbt[0];
  y0.y = (vals[1] - mean) * rs * fg[1] + fbt[1];
  y0.z = (vals[2] - mean) * rs * fg[2] + fbt[2];
  y0.w = (vals[3] - mean) * rs * fg[3] + fbt[3];
  y1.x = (vals[4] - mean) * rs * fg[4] + fbt[4];
  y1.y = (vals[5] - mean) * rs * fg[5] + fbt[5];
  y1.z = (vals[6] - mean) * rs * fg[6] + fbt[6];
  y1.w = (vals[7] - mean) * rs * fg[7] + fbt[7];
  *(float4*)(out + (size_t)row * 512 + d0) = y0;
  *(float4*)(out + (size_t)row * 512 + d0 + 4) = y1;
}

// ---------------------------------------------------------------------------
// Weight transposes (f32 in) into [N][K] bf16 layouts
// ---------------------------------------------------------------------------
__global__ __launch_bounds__(256) void prep_transpose(
    const float* __restrict__ Wq, const float* __restrict__ Wk,
    const float* __restrict__ Wv, const float* __restrict__ Wo,
    const float* __restrict__ Wg,
    unsigned short* __restrict__ WT1, unsigned short* __restrict__ WT2,
    unsigned short* __restrict__ WT3) {
  const int idx = blockIdx.x * 256 + threadIdx.x;
  if (idx < 786432) {  // WT1[n][k]: n = which*512 + h*64 + e
    const int n = idx >> 9, k = idx & 511;
    const int which = n >> 9, nn = n & 511;
    const int hh = nn >> 6, e = nn & 63;
    const float* W = (which == 0) ? Wq : (which == 1) ? Wk : Wv;
    WT1[idx] = f2bf(W[hh * 32768 + k * 64 + e]);
  } else if (idx < 786432 + 262144) {  // WT2[n][k] = Wo[k][n]
    const int i2 = idx - 786432;
    const int n = i2 >> 9, k = i2 & 511;
    WT2[i2] = f2bf(Wo[k * 512 + n]);
  } else {  // WT3[n'][k] = Wg[which][k][n]
    const int i3 = idx - 1048576;
    const int n = i3 >> 9, k = i3 & 511;
    const int which = n >> 9, nn = n & 511;
    WT3[i3] = f2bf(Wg[which * 262144 + k * 512 + nn]);
  }
}

// ---------------------------------------------------------------------------
// bias concat (f32) + adjacency row-softmax + neighbor lists
// ---------------------------------------------------------------------------
__global__ __launch_bounds__(256) void prep_small(
    const float* __restrict__ bq, const float* __restrict__ bk,
    const float* __restrict__ bv, const float* __restrict__ bo,
    const float* __restrict__ e, const int* __restrict__ rows,
    const int* __restrict__ cols, int nnz,
    float* __restrict__ bias1, float* __restrict__ bias2,
    float* __restrict__ Adiag, int* __restrict__ cnt,
    int* __restrict__ nbrk, float* __restrict__ nbrw) {
  const int t = threadIdx.x;
  for (int i = t; i < 1536; i += 256)
    bias1[i] = (i < 512) ? bq[i] : (i < 1024) ? bk[i - 512] : bv[i - 1024];
  for (int i = t; i < 512; i += 256) bias2[i] = bo[i];
  if (t < 17) {
    float m = -1e30f;
    for (int i = 0; i < nnz; ++i)
      if (rows[i] == t) m = fmaxf(m, e[i]);
    float s = 0.f;
    for (int i = 0; i < nnz; ++i)
      if (rows[i] == t) s += __expf(e[i] - m);
    const float inv = 1.f / s;
    int c = 0;
    for (int i = 0; i < nnz; ++i)
      if (rows[i] == t) {
        const float w = __expf(e[i] - m) * inv;
        const int kk = cols[i];
        if (kk == t) Adiag[t] = w;
        else { nbrk[t * 8 + c] = kk; nbrw[t * 8 + c] = w; ++c; }
      }
    cnt[t] = c;
  }
}

// ---------------------------------------------------------------------------
extern "C" void kernel_launch(void* const* d_in, const int* in_sizes, int n_in,
                              void* d_out, int out_size, void* d_ws, size_t ws_size,
                              hipStream_t stream) {
  const float* src = (const float*)d_in[0];
  const float* Wq  = (const float*)d_in[1];
  const float* bq  = (const float*)d_in[2];
  const float* Wk  = (const float*)d_in[3];
  const float* bk  = (const float*)d_in[4];
  const float* Wv  = (const float*)d_in[5];
  const float* bv  = (const float*)d_in[6];
  const float* Wo  = (const float*)d_in[7];
  const float* bo  = (const float*)d_in[8];
  const float* ln1g = (const float*)d_in[9];
  const float* ln1b = (const float*)d_in[10];
  const float* Wg  = (const float*)d_in[11];
  const float* eg  = (const float*)d_in[12];
  const float* bg  = (const float*)d_in[13];
  const float* ln2g = (const float*)d_in[14];
  const float* ln2b = (const float*)d_in[15];
  const int* mrows = (const int*)d_in[16];
  const int* mcols = (const int*)d_in[17];
  const int nnz = in_sizes[16];

  float* out = (float*)d_out;
  char* ws = (char*)d_ws;

  unsigned short* WT1 = (unsigned short*)(ws + 0x0000000);
  unsigned short* WT2 = (unsigned short*)(ws + 0x0180000);
  unsigned short* WT3 = (unsigned short*)(ws + 0x0200000);
  float* bias1 = (float*)(ws + 0x0300000);
  float* bias2 = (float*)(ws + 0x0302000);
  float* Adiag = (float*)(ws + 0x0303000);
  int* cnt     = (int*)(ws + 0x0303100);
  int* nbrk    = (int*)(ws + 0x0303200);
  float* nbrw  = (float*)(ws + 0x0303600);
  unsigned short* SRCB = (unsigned short*)(ws + 0x0400000);
  unsigned short* QKV  = (unsigned short*)(ws + 0x4800000);
  unsigned short* O    = (unsigned short*)(ws + 0x0400000);  // after SRCB dead
  unsigned short* ATT  = (unsigned short*)(ws + 0x4800000);  // after QKV dead
  unsigned short* X    = (unsigned short*)(ws + 0x8C00000);
  unsigned short* H01  = (unsigned short*)(ws + 0x0400000);  // after O/ATT dead

  (void)n_in; (void)out_size; (void)ws_size;

  convert_src<<<17408, 256, 0, stream>>>(src, SRCB);
  prep_transpose<<<6144, 256, 0, stream>>>(Wq, Wk, Wv, Wo, Wg, WT1, WT2, WT3);
  prep_small<<<1, 256, 0, stream>>>(bq, bk, bv, bo, eg, mrows, mcols, nnz,
                                    bias1, bias2, Adiag, cnt, nbrk, nbrw);
  gemm_bt<<<dim3(544, 12), 256, 0, stream>>>(SRCB, WT1, bias1, QKV, 1536);
  attn_kernel<<<dim3(4096, 8), 256, 0, stream>>>(QKV, O);
  gemm_bt<<<dim3(544, 4), 256, 0, stream>>>(O, WT2, bias2, ATT, 512);
  ln_res_kernel<<<17408, 256, 0, stream>>>(src, ATT, ln1g, ln1b, X);
  gemm_bt<<<dim3(544, 8), 256, 0, stream>>>(X, WT3, nullptr, H01, 1024);
  gcn_ln_kernel<<<17408, 256, 0, stream>>>(X, H01, Adiag, cnt, nbrk, nbrw, bg,
                                           ln2g, ln2b, out);
}

// Round 4
// 932.869 us; speedup vs baseline: 1.1795x; 1.1795x over previous
//
#include <hip/hip_runtime.h>

// ---------------------------------------------------------------------------
// ModifiedTransformerEncoderLayer on MI355X (gfx950)
// B=4096 J=17 D=512 H=8 DK=64, M=B*J=69632. I/O f32; compute bf16 MFMA.
//
// Round 4: (1) attn LDS stride 64->65 (bank-conflict fix, was 1.5e8 conflict
// cycles); (2) GEMM staging via __builtin_amdgcn_global_load_lds width=16
// with proper addrspacecast (m97 structure).
//
// ws layout (peak 0x11400000 = 276.1 MiB):
//   WT1 @0x000000  WT2 @0x180000  WT3 @0x200000  smalls @0x300000
//   SRCB @0x0400000 ; QKV @0x4800000 ; O @0x0400000 (SRCB dead)
//   ATT @0x4800000 (QKV dead) ; X @0x8C00000 ; H01 @0x0400000 (O/ATT dead)
// ---------------------------------------------------------------------------

typedef __attribute__((ext_vector_type(4))) float floatx4;
typedef __attribute__((ext_vector_type(8))) short short8;

#define AS1 __attribute__((address_space(1)))
#define AS3 __attribute__((address_space(3)))

__device__ __forceinline__ float bf2f(unsigned short u) {
  union { unsigned int i; float f; } x;
  x.i = ((unsigned int)u) << 16;
  return x.f;
}

__device__ __forceinline__ unsigned short f2bf(float f) {
  union { float f; unsigned int i; } x;
  x.f = f;
  unsigned int r = x.i + 0x7fffu + ((x.i >> 16) & 1u);  // RNE
  return (unsigned short)(r >> 16);
}

__device__ __forceinline__ void unpack8(uint4 u, float* f) {
  unsigned int uu[4] = {u.x, u.y, u.z, u.w};
#pragma unroll
  for (int i = 0; i < 4; ++i) {
    f[2 * i]     = bf2f((unsigned short)(uu[i] & 0xffffu));
    f[2 * i + 1] = bf2f((unsigned short)(uu[i] >> 16));
  }
}

__device__ __forceinline__ uint4 pack8(const float* f) {
  unsigned int uu[4];
#pragma unroll
  for (int i = 0; i < 4; ++i)
    uu[i] = (unsigned int)f2bf(f[2 * i]) | ((unsigned int)f2bf(f[2 * i + 1]) << 16);
  uint4 u; u.x = uu[0]; u.y = uu[1]; u.z = uu[2]; u.w = uu[3];
  return u;
}

__device__ __forceinline__ float wave_sum(float v) {
#pragma unroll
  for (int m = 1; m < 64; m <<= 1) v += __shfl_xor(v, m, 64);
  return v;
}

// async global->LDS, 16B/lane; LDS dest = wave-uniform base + lane*16
__device__ __forceinline__ void gload_lds16(const unsigned short* g, AS3 char* l) {
  __builtin_amdgcn_global_load_lds((const AS1 void*)g, (AS3 void*)l, 16, 0, 0);
}

// ---------------------------------------------------------------------------
// src f32 -> bf16, 8 elems/thread
// ---------------------------------------------------------------------------
__global__ __launch_bounds__(256) void convert_src(
    const float* __restrict__ in, unsigned short* __restrict__ out) {
  const size_t i = ((size_t)blockIdx.x * 256 + threadIdx.x) * 8;
  const float4 a = *(const float4*)(in + i);
  const float4 b = *(const float4*)(in + i + 4);
  const float f[8] = {a.x, a.y, a.z, a.w, b.x, b.y, b.z, b.w};
  *(uint4*)(out + i) = pack8(f);
}

// ---------------------------------------------------------------------------
// GEMM: C[M,N] = A[M,512] @ BT[N,512]^T (+ bias[N]), bf16 in/out, f32 accum.
// 128x128 tile, BK=32, 4 waves of 4x4 16x16x32 MFMA, async LDS staging.
// ---------------------------------------------------------------------------
__global__ __launch_bounds__(256) void gemm_bt(
    const unsigned short* __restrict__ A,
    const unsigned short* __restrict__ BT,
    const float* __restrict__ bias,
    unsigned short* __restrict__ C, int N) {
  __shared__ unsigned short As[128 * 32];
  __shared__ unsigned short Bs[128 * 32];
  const int t = threadIdx.x;
  const int wave = t >> 6;
  const int lane = t & 63;
  const int wm = wave >> 1, wn = wave & 1;
  const long rowBase = (long)blockIdx.x * 128;
  const long colBase = (long)blockIdx.y * 128;

  const unsigned short* a0 = A + (size_t)rowBase * 512;
  const unsigned short* b0 = BT + (size_t)colBase * 512;

  floatx4 acc[4][4];
#pragma unroll
  for (int i = 0; i < 4; ++i)
#pragma unroll
    for (int j = 0; j < 4; ++j) acc[i][j] = (floatx4){0.f, 0.f, 0.f, 0.f};

  // chunk c <-> (row=c>>2, kchunk=c&3); lane i of wave w stages chunks
  // w*64+i (pass 0) and 256+w*64+i (pass 1); LDS offset of chunk c = c*16 B.
  const size_t gOff0 = ((size_t)(t >> 2)) * 512 + (size_t)(t & 3) * 8;
  const size_t gOff1 = ((size_t)((t + 256) >> 2)) * 512 + (size_t)(t & 3) * 8;
  AS3 char* AsL = (AS3 char*)As;
  AS3 char* BsL = (AS3 char*)Bs;
  const int ldsOff0 = wave * 1024;         // (w*64 chunks)*16B
  const int ldsOff1 = 4096 + wave * 1024;  // (256+w*64)*16B

  const int am = lane & 15;
  const int aq = (lane >> 4) << 3;

  for (int k0 = 0; k0 < 512; k0 += 32) {
    __syncthreads();  // previous tile fully consumed
    gload_lds16(a0 + gOff0 + k0, AsL + ldsOff0);
    gload_lds16(a0 + gOff1 + k0, AsL + ldsOff1);
    gload_lds16(b0 + gOff0 + k0, BsL + ldsOff0);
    gload_lds16(b0 + gOff1 + k0, BsL + ldsOff1);
    __syncthreads();  // compiler drains vmcnt(0) before s_barrier

    short8 af[4], bf[4];
#pragma unroll
    for (int i = 0; i < 4; ++i)
      af[i] = *(const short8*)&As[(wm * 64 + i * 16 + am) * 32 + aq];
#pragma unroll
    for (int j = 0; j < 4; ++j)
      bf[j] = *(const short8*)&Bs[(wn * 64 + j * 16 + am) * 32 + aq];
#pragma unroll
    for (int i = 0; i < 4; ++i)
#pragma unroll
      for (int j = 0; j < 4; ++j)
        acc[i][j] = __builtin_amdgcn_mfma_f32_16x16x32_bf16(af[i], bf[j], acc[i][j], 0, 0, 0);
  }

  // epilogue: C/D layout col=lane&15, row=(lane>>4)*4+reg  [m89-verified]
  const int q4 = (lane >> 4) << 2;
#pragma unroll
  for (int i = 0; i < 4; ++i) {
#pragma unroll
    for (int j = 0; j < 4; ++j) {
      const long col = colBase + wn * 64 + j * 16 + am;
      const float badd = bias ? bias[col] : 0.f;
      const long rowa = rowBase + wm * 64 + i * 16 + q4;
#pragma unroll
      for (int r = 0; r < 4; ++r)
        C[(size_t)(rowa + r) * N + col] = f2bf(acc[i][j][r] + badd);
    }
  }
}

// ---------------------------------------------------------------------------
// Per-(b,h) attention. LDS stride 65 (65 % 32 == 1): lanes with distinct
// j/kk land in distinct banks -> conflict-free scalar reads.
// ---------------------------------------------------------------------------
__global__ __launch_bounds__(256) void attn_kernel(
    const unsigned short* __restrict__ qkv, unsigned short* __restrict__ o) {
  const int b = blockIdx.x, h = blockIdx.y;
  __shared__ float q[17][65], k[17][65], v[17][65];
  __shared__ float S[17][17];
  const int t = threadIdx.x;
  const unsigned short* base = qkv + (size_t)b * 17 * 1536 + h * 64;

  for (int idx = t; idx < 3 * 136; idx += 256) {  // 136 = 17 rows * 8 chunks
    const int m = idx / 136, rem = idx - m * 136;
    const int r = rem >> 3, e0 = (rem & 7) << 3;
    uint4 u = *(const uint4*)(base + (size_t)r * 1536 + m * 512 + e0);
    float f[8];
    unpack8(u, f);
    float(*dst)[65] = (m == 0) ? q : (m == 1) ? k : v;
#pragma unroll
    for (int e = 0; e < 8; ++e) dst[r][e0 + e] = f[e];
  }
  __syncthreads();

  for (int idx = t; idx < 289; idx += 256) {
    const int j = idx / 17, kk = idx - j * 17;
    float s = 0.f;
#pragma unroll 8
    for (int e = 0; e < 64; ++e) s += q[j][e] * k[kk][e];
    S[j][kk] = s * 0.125f;  // / sqrt(64)
  }
  __syncthreads();

  if (t < 17) {
    float m = -1e30f;
#pragma unroll
    for (int kk = 0; kk < 17; ++kk) m = fmaxf(m, S[t][kk]);
    float tmp[17], sum = 0.f;
#pragma unroll
    for (int kk = 0; kk < 17; ++kk) { tmp[kk] = __expf(S[t][kk] - m); sum += tmp[kk]; }
    const float inv = 1.f / sum;
#pragma unroll
    for (int kk = 0; kk < 17; ++kk) S[t][kk] = tmp[kk] * inv;
  }
  __syncthreads();

  unsigned short* ob = o + (size_t)b * 17 * 512 + h * 64;
  for (int idx = t; idx < 136; idx += 256) {
    const int j = idx >> 3, e0 = (idx & 7) << 3;
    float ov[8] = {0, 0, 0, 0, 0, 0, 0, 0};
#pragma unroll
    for (int kk = 0; kk < 17; ++kk) {
      const float a = S[j][kk];
#pragma unroll
      for (int e = 0; e < 8; ++e) ov[e] += a * v[kk][e0 + e];
    }
    *(uint4*)(ob + (size_t)j * 512 + e0) = pack8(ov);
  }
}

// ---------------------------------------------------------------------------
// X = LN1(src_f32 + att_bf16; g,beta f32) -> bf16. One wave per row.
// ---------------------------------------------------------------------------
__global__ __launch_bounds__(256) void ln_res_kernel(
    const float* __restrict__ a, const unsigned short* __restrict__ b,
    const float* __restrict__ g, const float* __restrict__ beta,
    unsigned short* __restrict__ out) {
  const long row = (long)blockIdx.x * 4 + (threadIdx.x >> 6);
  const int lane = threadIdx.x & 63;
  const int d0 = lane * 8;

  const float4 a0 = *(const float4*)(a + (size_t)row * 512 + d0);
  const float4 a1 = *(const float4*)(a + (size_t)row * 512 + d0 + 4);
  const float fa[8] = {a0.x, a0.y, a0.z, a0.w, a1.x, a1.y, a1.z, a1.w};
  float fb[8], vals[8];
  unpack8(*(const uint4*)(b + (size_t)row * 512 + d0), fb);
  float s = 0.f, s2 = 0.f;
#pragma unroll
  for (int i = 0; i < 8; ++i) {
    vals[i] = fa[i] + fb[i];
    s += vals[i];
    s2 += vals[i] * vals[i];
  }
  const float mean = wave_sum(s) * (1.f / 512.f);
  const float var = wave_sum(s2) * (1.f / 512.f) - mean * mean;
  const float rs = rsqrtf(var + 1e-5f);

  const float4 g0 = *(const float4*)(g + d0);
  const float4 g1 = *(const float4*)(g + d0 + 4);
  const float4 b0 = *(const float4*)(beta + d0);
  const float4 b1 = *(const float4*)(beta + d0 + 4);
  const float fg[8]  = {g0.x, g0.y, g0.z, g0.w, g1.x, g1.y, g1.z, g1.w};
  const float fbt[8] = {b0.x, b0.y, b0.z, b0.w, b1.x, b1.y, b1.z, b1.w};
  float y[8];
#pragma unroll
  for (int i = 0; i < 8; ++i) y[i] = (vals[i] - mean) * rs * fg[i] + fbt[i];
  *(uint4*)(out + (size_t)row * 512 + d0) = pack8(y);
}

// ---------------------------------------------------------------------------
// out_f32 = LN2(x + gcn + b_gcn); gcn = Adiag[j]*h0[row] + sum_nbr w*h1[b,k]
// ---------------------------------------------------------------------------
__global__ __launch_bounds__(256) void gcn_ln_kernel(
    const unsigned short* __restrict__ x, const unsigned short* __restrict__ h01,
    const float* __restrict__ Adiag, const int* __restrict__ cnt,
    const int* __restrict__ nbrk, const float* __restrict__ nbrw,
    const float* __restrict__ bgcn,
    const float* __restrict__ g, const float* __restrict__ beta,
    float* __restrict__ out) {
  const long row = (long)blockIdx.x * 4 + (threadIdx.x >> 6);
  const int lane = threadIdx.x & 63;
  const int b = (int)(row / 17);
  const int j = (int)(row - (long)b * 17);
  const int d0 = lane * 8;

  float accv[8];
  {
    const float w = Adiag[j];
    float f[8];
    unpack8(*(const uint4*)(h01 + (size_t)row * 1024 + d0), f);
#pragma unroll
    for (int i = 0; i < 8; ++i) accv[i] = w * f[i];
  }
  const int c = cnt[j];
  for (int nb = 0; nb < c; ++nb) {
    const int kk = nbrk[j * 8 + nb];
    const float w = nbrw[j * 8 + nb];
    float f[8];
    unpack8(*(const uint4*)(h01 + ((size_t)b * 17 + kk) * 1024 + 512 + d0), f);
#pragma unroll
    for (int i = 0; i < 8; ++i) accv[i] += w * f[i];
  }

  float fx[8], vals[8];
  unpack8(*(const uint4*)(x + (size_t)row * 512 + d0), fx);
  const float4 bg0 = *(const float4*)(bgcn + d0);
  const float4 bg1 = *(const float4*)(bgcn + d0 + 4);
  const float fbg[8] = {bg0.x, bg0.y, bg0.z, bg0.w, bg1.x, bg1.y, bg1.z, bg1.w};
  float s = 0.f, s2 = 0.f;
#pragma unroll
  for (int i = 0; i < 8; ++i) {
    vals[i] = fx[i] + accv[i] + fbg[i];
    s += vals[i];
    s2 += vals[i] * vals[i];
  }
  const float mean = wave_sum(s) * (1.f / 512.f);
  const float var = wave_sum(s2) * (1.f / 512.f) - mean * mean;
  const float rs = rsqrtf(var + 1e-5f);

  const float4 g0 = *(const float4*)(g + d0);
  const float4 g1 = *(const float4*)(g + d0 + 4);
  const float4 bb0 = *(const float4*)(beta + d0);
  const float4 bb1 = *(const float4*)(beta + d0 + 4);
  const float fg[8]  = {g0.x, g0.y, g0.z, g0.w, g1.x, g1.y, g1.z, g1.w};
  const float fbt[8] = {bb0.x, bb0.y, bb0.z, bb0.w, bb1.x, bb1.y, bb1.z, bb1.w};
  float4 y0, y1;
  y0.x = (vals[0] - mean) * rs * fg[0] + fbt[0];
  y0.y = (vals[1] - mean) * rs * fg[1] + fbt[1];
  y0.z = (vals[2] - mean) * rs * fg[2] + fbt[2];
  y0.w = (vals[3] - mean) * rs * fg[3] + fbt[3];
  y1.x = (vals[4] - mean) * rs * fg[4] + fbt[4];
  y1.y = (vals[5] - mean) * rs * fg[5] + fbt[5];
  y1.z = (vals[6] - mean) * rs * fg[6] + fbt[6];
  y1.w = (vals[7] - mean) * rs * fg[7] + fbt[7];
  *(float4*)(out + (size_t)row * 512 + d0) = y0;
  *(float4*)(out + (size_t)row * 512 + d0 + 4) = y1;
}

// ---------------------------------------------------------------------------
// Weight transposes (f32 in) into [N][K] bf16 layouts
// ---------------------------------------------------------------------------
__global__ __launch_bounds__(256) void prep_transpose(
    const float* __restrict__ Wq, const float* __restrict__ Wk,
    const float* __restrict__ Wv, const float* __restrict__ Wo,
    const float* __restrict__ Wg,
    unsigned short* __restrict__ WT1, unsigned short* __restrict__ WT2,
    unsigned short* __restrict__ WT3) {
  const int idx = blockIdx.x * 256 + threadIdx.x;
  if (idx < 786432) {  // WT1[n][k]: n = which*512 + h*64 + e
    const int n = idx >> 9, k = idx & 511;
    const int which = n >> 9, nn = n & 511;
    const int hh = nn >> 6, e = nn & 63;
    const float* W = (which == 0) ? Wq : (which == 1) ? Wk : Wv;
    WT1[idx] = f2bf(W[hh * 32768 + k * 64 + e]);
  } else if (idx < 786432 + 262144) {  // WT2[n][k] = Wo[k][n]
    const int i2 = idx - 786432;
    const int n = i2 >> 9, k = i2 & 511;
    WT2[i2] = f2bf(Wo[k * 512 + n]);
  } else {  // WT3[n'][k] = Wg[which][k][n]
    const int i3 = idx - 1048576;
    const int n = i3 >> 9, k = i3 & 511;
    const int which = n >> 9, nn = n & 511;
    WT3[i3] = f2bf(Wg[which * 262144 + k * 512 + nn]);
  }
}

// ---------------------------------------------------------------------------
// bias concat (f32) + adjacency row-softmax + neighbor lists
// ---------------------------------------------------------------------------
__global__ __launch_bounds__(256) void prep_small(
    const float* __restrict__ bq, const float* __restrict__ bk,
    const float* __restrict__ bv, const float* __restrict__ bo,
    const float* __restrict__ e, const int* __restrict__ rows,
    const int* __restrict__ cols, int nnz,
    float* __restrict__ bias1, float* __restrict__ bias2,
    float* __restrict__ Adiag, int* __restrict__ cnt,
    int* __restrict__ nbrk, float* __restrict__ nbrw) {
  const int t = threadIdx.x;
  for (int i = t; i < 1536; i += 256)
    bias1[i] = (i < 512) ? bq[i] : (i < 1024) ? bk[i - 512] : bv[i - 1024];
  for (int i = t; i < 512; i += 256) bias2[i] = bo[i];
  if (t < 17) {
    float m = -1e30f;
    for (int i = 0; i < nnz; ++i)
      if (rows[i] == t) m = fmaxf(m, e[i]);
    float s = 0.f;
    for (int i = 0; i < nnz; ++i)
      if (rows[i] == t) s += __expf(e[i] - m);
    const float inv = 1.f / s;
    int c = 0;
    for (int i = 0; i < nnz; ++i)
      if (rows[i] == t) {
        const float w = __expf(e[i] - m) * inv;
        const int kk = cols[i];
        if (kk == t) Adiag[t] = w;
        else { nbrk[t * 8 + c] = kk; nbrw[t * 8 + c] = w; ++c; }
      }
    cnt[t] = c;
  }
}

// ---------------------------------------------------------------------------
extern "C" void kernel_launch(void* const* d_in, const int* in_sizes, int n_in,
                              void* d_out, int out_size, void* d_ws, size_t ws_size,
                              hipStream_t stream) {
  const float* src = (const float*)d_in[0];
  const float* Wq  = (const float*)d_in[1];
  const float* bq  = (const float*)d_in[2];
  const float* Wk  = (const float*)d_in[3];
  const float* bk  = (const float*)d_in[4];
  const float* Wv  = (const float*)d_in[5];
  const float* bv  = (const float*)d_in[6];
  const float* Wo  = (const float*)d_in[7];
  const float* bo  = (const float*)d_in[8];
  const float* ln1g = (const float*)d_in[9];
  const float* ln1b = (const float*)d_in[10];
  const float* Wg  = (const float*)d_in[11];
  const float* eg  = (const float*)d_in[12];
  const float* bg  = (const float*)d_in[13];
  const float* ln2g = (const float*)d_in[14];
  const float* ln2b = (const float*)d_in[15];
  const int* mrows = (const int*)d_in[16];
  const int* mcols = (const int*)d_in[17];
  const int nnz = in_sizes[16];

  float* out = (float*)d_out;
  char* ws = (char*)d_ws;

  unsigned short* WT1 = (unsigned short*)(ws + 0x0000000);
  unsigned short* WT2 = (unsigned short*)(ws + 0x0180000);
  unsigned short* WT3 = (unsigned short*)(ws + 0x0200000);
  float* bias1 = (float*)(ws + 0x0300000);
  float* bias2 = (float*)(ws + 0x0302000);
  float* Adiag = (float*)(ws + 0x0303000);
  int* cnt     = (int*)(ws + 0x0303100);
  int* nbrk    = (int*)(ws + 0x0303200);
  float* nbrw  = (float*)(ws + 0x0303600);
  unsigned short* SRCB = (unsigned short*)(ws + 0x0400000);
  unsigned short* QKV  = (unsigned short*)(ws + 0x4800000);
  unsigned short* O    = (unsigned short*)(ws + 0x0400000);  // after SRCB dead
  unsigned short* ATT  = (unsigned short*)(ws + 0x4800000);  // after QKV dead
  unsigned short* X    = (unsigned short*)(ws + 0x8C00000);
  unsigned short* H01  = (unsigned short*)(ws + 0x0400000);  // after O/ATT dead

  (void)n_in; (void)out_size; (void)ws_size;

  convert_src<<<17408, 256, 0, stream>>>(src, SRCB);
  prep_transpose<<<6144, 256, 0, stream>>>(Wq, Wk, Wv, Wo, Wg, WT1, WT2, WT3);
  prep_small<<<1, 256, 0, stream>>>(bq, bk, bv, bo, eg, mrows, mcols, nnz,
                                    bias1, bias2, Adiag, cnt, nbrk, nbrw);
  gemm_bt<<<dim3(544, 12), 256, 0, stream>>>(SRCB, WT1, bias1, QKV, 1536);
  attn_kernel<<<dim3(4096, 8), 256, 0, stream>>>(QKV, O);
  gemm_bt<<<dim3(544, 4), 256, 0, stream>>>(O, WT2, bias2, ATT, 512);
  ln_res_kernel<<<17408, 256, 0, stream>>>(src, ATT, ln1g, ln1b, X);
  gemm_bt<<<dim3(544, 8), 256, 0, stream>>>(X, WT3, nullptr, H01, 1024);
  gcn_ln_kernel<<<17408, 256, 0, stream>>>(X, H01, Adiag, cnt, nbrk, nbrw, bg,
                                           ln2g, ln2b, out);
}